// Round 6
// baseline (230.384 us; speedup 1.0000x reference)
//
#include <hip/hip_runtime.h>
#include <hip/hip_bf16.h>

typedef short s8v __attribute__((ext_vector_type(8)));
typedef float f4v __attribute__((ext_vector_type(4)));
typedef unsigned short u16;
typedef unsigned int u32;

// B=2, T=192, C=512, H=8, HS=64, ORDER=3; scale = 1/sqrt(64) = 0.125
#define SPLIT 4
#define ESC 0.18033688011112042f  // 0.125 * log2(e), folded into Q at proj

// Fast bf16 conversion: round-half-up (add 0x8000) — 3 VALU ops per pair.
__device__ __forceinline__ u32 pack2bf(float lo, float hi) {
  u32 a = __builtin_bit_cast(u32, lo) + 0x8000u;
  u32 b = __builtin_bit_cast(u32, hi) + 0x8000u;
  return __builtin_amdgcn_perm(b, a, 0x07060302);  // {hi[31:16], lo[31:16]}
}
__device__ __forceinline__ u16 bf1(float f) {
  return (u16)((__builtin_bit_cast(u32, f) + 0x8000u) >> 16);
}
__device__ __forceinline__ f4v mfma16(s8v a, s8v b, f4v c) {
  return __builtin_amdgcn_mfma_f32_16x16x32_bf16(a, b, c, 0, 0, 0);
}

// ---------------- projection kernel (MFMA) ----------------
// grid = 5 slots * 16 bh = 80 blocks, 256 threads (4 waves).
// Per block: out[192][64] = x(192x512) @ w^T(512x64) + bias, bf16 MFMA with
// fp32 accumulate. K staged in 8 chunks of 64. Wave w owns rows [48w,48w+48).
__global__ __launch_bounds__(256) void proj_kernel(
    const float* __restrict__ x0, const float* __restrict__ x1,
    const float* __restrict__ x2,
    const float* __restrict__ qw, const float* __restrict__ qb,
    const float* __restrict__ kw, const float* __restrict__ kb,
    const float* __restrict__ vw, const float* __restrict__ vb,
    float* __restrict__ Q0f, float* __restrict__ K1f, float* __restrict__ V1f,
    u16* __restrict__ K2b, u16* __restrict__ V2b) {
  __shared__ u16 xs[192 * 68];  // row stride 68 u16 = 136 B (17 dwords, odd)
  __shared__ u16 wsx[64 * 68];

  int bx = blockIdx.x;
  int slot = bx / 16;
  int bh = bx - slot * 16;
  int b = bh >> 3, h = bh & 7;

  const float* x; const float* w; const float* bias; int o;
  float* outf = nullptr; u16* outb = nullptr;
  switch (slot) {
    case 0: x = x0; w = qw; bias = qb; o = 0; outf = Q0f; break;
    case 1: x = x1; w = kw; bias = kb; o = 1; outf = K1f; break;
    case 2: x = x2; w = kw; bias = kb; o = 2; outb = K2b; break;
    case 3: x = x1; w = vw; bias = vb; o = 1; outf = V1f; break;
    default: x = x2; w = vw; bias = vb; o = 2; outb = V2b; break;
  }
  x += b * 192 * 512;
  w += (h * 3 + o) * 64 * 512;
  bias += (h * 3 + o) * 64;

  int tid = threadIdx.x;
  int wave = tid >> 6;
  int lane = tid & 63;
  int l15 = lane & 15;
  int quad = lane >> 4;

  f4v acc[3][4] = {};  // 3 m-tiles x 4 n-tiles per wave

  for (int kc = 0; kc < 8; ++kc) {
    int c0 = kc * 64;
#pragma unroll
    for (int r = 0; r < 12; ++r) {  // stage x chunk 192 x 64 -> bf16
      int idx = r * 256 + tid;
      int row = idx >> 4, c4 = idx & 15;
      float4 v = *(const float4*)(x + row * 512 + c0 + c4 * 4);
      uint2 st = {pack2bf(v.x, v.y), pack2bf(v.z, v.w)};
      *(uint2*)(xs + row * 68 + c4 * 4) = st;
    }
#pragma unroll
    for (int r = 0; r < 4; ++r) {  // stage w chunk 64 x 64 -> bf16
      int idx = r * 256 + tid;
      int row = idx >> 4, c4 = idx & 15;
      float4 v = *(const float4*)(w + row * 512 + c0 + c4 * 4);
      uint2 st = {pack2bf(v.x, v.y), pack2bf(v.z, v.w)};
      *(uint2*)(wsx + row * 68 + c4 * 4) = st;
    }
    __syncthreads();
#pragma unroll
    for (int kst = 0; kst < 2; ++kst) {
      s8v a0 = *(const s8v*)(xs + (wave * 48 + l15) * 68 + kst * 32 + quad * 8);
      s8v a1 = *(const s8v*)(xs + (wave * 48 + 16 + l15) * 68 + kst * 32 + quad * 8);
      s8v a2 = *(const s8v*)(xs + (wave * 48 + 32 + l15) * 68 + kst * 32 + quad * 8);
      s8v b0 = *(const s8v*)(wsx + (l15)*68 + kst * 32 + quad * 8);
      s8v b1 = *(const s8v*)(wsx + (16 + l15) * 68 + kst * 32 + quad * 8);
      s8v b2 = *(const s8v*)(wsx + (32 + l15) * 68 + kst * 32 + quad * 8);
      s8v b3 = *(const s8v*)(wsx + (48 + l15) * 68 + kst * 32 + quad * 8);
      acc[0][0] = mfma16(a0, b0, acc[0][0]);
      acc[0][1] = mfma16(a0, b1, acc[0][1]);
      acc[0][2] = mfma16(a0, b2, acc[0][2]);
      acc[0][3] = mfma16(a0, b3, acc[0][3]);
      acc[1][0] = mfma16(a1, b0, acc[1][0]);
      acc[1][1] = mfma16(a1, b1, acc[1][1]);
      acc[1][2] = mfma16(a1, b2, acc[1][2]);
      acc[1][3] = mfma16(a1, b3, acc[1][3]);
      acc[2][0] = mfma16(a2, b0, acc[2][0]);
      acc[2][1] = mfma16(a2, b1, acc[2][1]);
      acc[2][2] = mfma16(a2, b2, acc[2][2]);
      acc[2][3] = mfma16(a2, b3, acc[2][3]);
    }
    __syncthreads();
  }

  float bias_n[4];
#pragma unroll
  for (int nt = 0; nt < 4; ++nt) bias_n[nt] = bias[nt * 16 + l15];
  float scl = (slot == 0) ? ESC : 1.0f;
#pragma unroll
  for (int i = 0; i < 3; ++i)
#pragma unroll
    for (int nt = 0; nt < 4; ++nt)
#pragma unroll
      for (int r = 0; r < 4; ++r) {
        int t = wave * 48 + i * 16 + quad * 4 + r;
        float v = (acc[i][nt][r] + bias_n[nt]) * scl;
        long base = ((long)(bh * 192 + t)) * 64 + nt * 16 + l15;
        if (outf) outf[base] = v;
        else outb[base] = bf1(v);
      }
}

// ---------------- attention kernel ----------------
// grid = SPLIT*16*12 = 768 blocks, 256 threads (4 waves).
// Software-pipelined: C(m-1) interleaved with B(m) at jj granularity — P-frag
// LDS reads issue first, B's VALU hides their latency, one barrier per batch.
// P row stride 408 B (dword stride 102 ≡ 2 mod 4) => all-16-distinct l15 bank
// starts on the C-phase b128 reads (was 4-way-aliased at 400).
// LDS = 52224 B: staging K2 [0,24576) + V2T [24576,50176); then P double
// buffer 2 x 26112 overlapping both (frags consumed to registers first).
__global__ __launch_bounds__(256) void attn_kernel(
    const float* __restrict__ Q0f, const float* __restrict__ K1f,
    const float* __restrict__ V1f, const u16* __restrict__ K2b,
    const u16* __restrict__ V2b, float* __restrict__ Op,
    float* __restrict__ lp) {
  extern __shared__ char smem[];
  int bx = blockIdx.x;
  int sp = bx / 192;
  int rem = bx - sp * 192;
  int bh = rem / 12;
  int itile = rem - bh * 12;
  int i0 = itile * 16;
  int js = sp * 48;
  int tid = threadIdx.x;
  int wave = tid >> 6;
  int lane = tid & 63;
  int l15 = lane & 15;
  int quad = lane >> 4;

  u16* V2Ts = (u16*)(smem + 24576);  // [64 d][200] u16, phys-interleaved k
  {
    const u32* src = (const u32*)K2b + bh * 6144;
#pragma unroll
    for (int r = 0; r < 24; ++r) {  // K2 as [192 k][64] u16 (stride 128 B)
      int idx = r * 256 + tid;
      int k = idx >> 5, d2 = idx & 31;
      *(u32*)(smem + k * 128 + d2 * 4) = src[idx];
    }
    const u32* vsrc = (const u32*)V2b + bh * 6144;
#pragma unroll
    for (int r = 0; r < 24; ++r) {  // V2^T with phys(k) interleave
      int idx = r * 256 + tid;
      int k = idx >> 5, d2 = idx & 31;
      u32 v = vsrc[idx];
      int wv = (k * 1366) >> 16;  // k/48
      int c = k - wv * 48;
      int phys = c < 32 ? wv * 32 + ((c & 15) << 1) + (c >> 4)
                        : 128 + wv * 16 + (c & 15);
      V2Ts[(d2 * 2) * 200 + phys] = (u16)v;
      V2Ts[(d2 * 2 + 1) * 200 + phys] = (u16)(v >> 16);
    }
  }
  __syncthreads();

  s8v k2f[3][2];  // S matmul: B[k=d][n=kcol] = K2[kcol][d]
#pragma unroll
  for (int nt = 0; nt < 3; ++nt)
#pragma unroll
    for (int ks = 0; ks < 2; ++ks) {
      int n = wave * 48 + nt * 16 + l15;
      k2f[nt][ks] = *(const s8v*)(smem + n * 128 + ks * 64 + quad * 16);
    }
  s8v v2f[6];  // PV matmul: B[kphys][n=d]
#pragma unroll
  for (int ks = 0; ks < 6; ++ks) {
    int d = wave * 16 + l15;
    v2f[ks] = *(const s8v*)((const char*)V2Ts + d * 400 + ks * 64 + quad * 16);
  }
  __syncthreads();

  // Q (pre-scaled by ESC at proj) in the exact A-fragment slots:
  const float4* qp = (const float4*)(Q0f + (bh * 192 + i0 + l15) * 64);
  float4 q0 = qp[quad * 2], q1 = qp[quad * 2 + 1];
  float4 q2 = qp[8 + quad * 2], q3 = qp[9 + quad * 2];

  float Oacc[4] = {0.f, 0.f, 0.f, 0.f};
  float lacc[4] = {0.f, 0.f, 0.f, 0.f};
  const int dcol = wave * 16 + l15;

  // B-phase for one jj: build A-frags, 6 MFMA, exp, write P to psj.
#define B_PHASE(JGLOB, PSJ)                                                  \
  {                                                                          \
    const float4* kp = (const float4*)(K1f + (bh * 192 + (JGLOB)) * 64);     \
    float4 c0 = kp[quad * 2], c1 = kp[quad * 2 + 1];                         \
    float4 c2 = kp[8 + quad * 2], c3 = kp[9 + quad * 2];                     \
    union { s8v v; u32 w[4]; } A0, A1;                                       \
    A0.w[0] = pack2bf(q0.x * c0.x, q0.y * c0.y);                             \
    A0.w[1] = pack2bf(q0.z * c0.z, q0.w * c0.w);                             \
    A0.w[2] = pack2bf(q1.x * c1.x, q1.y * c1.y);                             \
    A0.w[3] = pack2bf(q1.z * c1.z, q1.w * c1.w);                             \
    A1.w[0] = pack2bf(q2.x * c2.x, q2.y * c2.y);                             \
    A1.w[1] = pack2bf(q2.z * c2.z, q2.w * c2.w);                             \
    A1.w[2] = pack2bf(q3.x * c3.x, q3.y * c3.y);                             \
    A1.w[3] = pack2bf(q3.z * c3.z, q3.w * c3.w);                             \
    f4v sc0 = {0.f, 0.f, 0.f, 0.f}, sc1 = sc0, sc2 = sc0;                    \
    sc0 = mfma16(A0.v, k2f[0][0], sc0); sc0 = mfma16(A1.v, k2f[0][1], sc0);  \
    sc1 = mfma16(A0.v, k2f[1][0], sc1); sc1 = mfma16(A1.v, k2f[1][1], sc1);  \
    sc2 = mfma16(A0.v, k2f[2][0], sc2); sc2 = mfma16(A1.v, k2f[2][1], sc2);  \
    _Pragma("unroll") for (int r = 0; r < 4; ++r) {                          \
      float p0 = __builtin_amdgcn_exp2f(sc0[r]);                             \
      float p1 = __builtin_amdgcn_exp2f(sc1[r]);                             \
      float p2 = __builtin_amdgcn_exp2f(sc2[r]);                             \
      int row = quad * 4 + r;                                                \
      *(u32*)((PSJ) + row * 204 + wave * 32 + l15 * 2) = pack2bf(p0, p1);    \
      (PSJ)[row * 204 + 128 + wave * 16 + l15] = bf1(p2);                    \
      lacc[r] += p0 + p1 + p2;                                               \
    }                                                                        \
  }

  float v1p[4];  // V1 for the batch being consumed by C
#pragma unroll
  for (int jj = 0; jj < 4; ++jj)
    v1p[jj] = V1f[(bh * 192 + js + jj) * 64 + dcol];

  // ---- prologue: B(first batch) -> PS[0]
  {
    u16* PSc = (u16*)smem;
#pragma unroll
    for (int jj = 0; jj < 4; ++jj) {
      u16* psj = PSc + jj * 3264;
      B_PHASE(js + jj, psj)
    }
  }
  __syncthreads();

  int buf = 0;  // PS[buf] holds the batch to consume
  for (int j0 = js + 4; j0 < js + 48; j0 += 4) {
    u16* PSp = (u16*)(smem + buf * 26112);
    u16* PSc = (u16*)(smem + (buf ^ 1) * 26112);
    float v1n[4];
#pragma unroll
    for (int jj = 0; jj < 4; ++jj)
      v1n[jj] = V1f[(bh * 192 + j0 + jj) * 64 + dcol];

#pragma unroll
    for (int jj = 0; jj < 4; ++jj) {
      // C-loads (prev batch) issue first; latency hidden by B's VALU
      const char* pb = (const char*)PSp + jj * 6528 + l15 * 408;
      s8v pf0 = *(const s8v*)(pb);
      s8v pf1 = *(const s8v*)(pb + 64);
      s8v pf2 = *(const s8v*)(pb + 128);
      s8v pf3 = *(const s8v*)(pb + 192);
      s8v pf4 = *(const s8v*)(pb + 256);
      s8v pf5 = *(const s8v*)(pb + 320);
      u16* psj = PSc + jj * 3264;
      B_PHASE(j0 + jj, psj)
      f4v w4 = {0.f, 0.f, 0.f, 0.f};
      w4 = mfma16(pf0, v2f[0], w4);
      w4 = mfma16(pf1, v2f[1], w4);
      w4 = mfma16(pf2, v2f[2], w4);
      w4 = mfma16(pf3, v2f[3], w4);
      w4 = mfma16(pf4, v2f[4], w4);
      w4 = mfma16(pf5, v2f[5], w4);
#pragma unroll
      for (int r = 0; r < 4; ++r) Oacc[r] += v1p[jj] * w4[r];
    }
    __syncthreads();
    buf ^= 1;
#pragma unroll
    for (int jj = 0; jj < 4; ++jj) v1p[jj] = v1n[jj];
  }

  // ---- epilogue C: consume last batch from PS[buf]
#pragma unroll
  for (int jj = 0; jj < 4; ++jj) {
    const char* pb = (const char*)(smem + buf * 26112) + jj * 6528 + l15 * 408;
    f4v w4 = {0.f, 0.f, 0.f, 0.f};
#pragma unroll
    for (int ks = 0; ks < 6; ++ks)
      w4 = mfma16(*(const s8v*)(pb + ks * 64 + quad * 16), v2f[ks], w4);
#pragma unroll
    for (int r = 0; r < 4; ++r) Oacc[r] += v1p[jj] * w4[r];
  }
  __syncthreads();

  // ---- epilogue: reduce l across lanes/waves, store partials
#pragma unroll
  for (int r = 0; r < 4; ++r)
#pragma unroll
    for (int off = 1; off < 16; off <<= 1)
      lacc[r] += __shfl_xor(lacc[r], off);
  float* lred = (float*)smem;
  if (l15 == 0) {
#pragma unroll
    for (int r = 0; r < 4; ++r) lred[wave * 16 + quad * 4 + r] = lacc[r];
  }
  __syncthreads();

  long obase = (long)(sp * 16 + bh) * 192 + i0;
#pragma unroll
  for (int r = 0; r < 4; ++r)
    Op[(obase + quad * 4 + r) * 64 + dcol] = Oacc[r];
  if (tid < 16)
    lp[(sp * 16 + bh) * 192 + i0 + tid] =
        lred[tid] + lred[16 + tid] + lred[32 + tid] + lred[48 + tid];
}

// ---------------- output projection (split-combine + 1/l fused) ----------
// grid = 24 mt(16) * 8 nt(64) = 192 blocks, register-dbuf staging.
__global__ __launch_bounds__(256) void outproj_kernel(
    const float* __restrict__ Op, const float* __restrict__ lp,
    const float* __restrict__ cw, const float* __restrict__ cb,
    float* __restrict__ out) {
  __shared__ float xs[32][20];   // [c][m]
  __shared__ float wsh[32][68];  // [c][n]
  __shared__ float linv[8][16];  // [h][m]
  int bx = blockIdx.x;
  int mt = bx >> 3, nt = bx & 7;
  int m0 = mt * 16;
  int b = m0 / 192;
  int t0 = m0 - b * 192;
  int n0 = nt * 64;
  int tid = threadIdx.x;

  if (tid < 128) {
    int h = tid >> 4, ml = tid & 15;
    float s = 0.f;
#pragma unroll
    for (int sp = 0; sp < SPLIT; ++sp)
      s += lp[(sp * 16 + b * 8 + h) * 192 + t0 + ml];
    linv[h][ml] = 1.0f / s;
  }

  int mA = tid >> 3, clA = (tid & 7) * 4;  // A-stage (tid<128 only)
  int nB0 = tid >> 3, nB1 = (256 + tid) >> 3;
  int m = tid >> 4, nq = tid & 15;
  float acc[4] = {};

  float4 pA[SPLIT];
  float4 pW0, pW1;
  {  // prefetch kc = 0 (h=0, d0=0)
    if (tid < 128) {
#pragma unroll
      for (int sp = 0; sp < SPLIT; ++sp)
        pA[sp] = *(const float4*)(
            Op + (long)((sp * 16 + b * 8) * 192 + t0 + mA) * 64 + clA);
    }
    pW0 = *(const float4*)(cw + (long)(n0 + nB0) * 512 + clA);
    pW1 = *(const float4*)(cw + (long)(n0 + nB1) * 512 + clA);
  }
  __syncthreads();  // linv ready

  for (int kc = 0; kc < 16; ++kc) {
    int h = kc >> 1;
    if (tid < 128) {  // combine SPLIT partials, scale 1/l, store [c][m]
      float4 s = pA[0];
#pragma unroll
      for (int sp = 1; sp < SPLIT; ++sp) {
        s.x += pA[sp].x; s.y += pA[sp].y; s.z += pA[sp].z; s.w += pA[sp].w;
      }
      float li = linv[h][mA];
      xs[clA][mA] = s.x * li; xs[clA + 1][mA] = s.y * li;
      xs[clA + 2][mA] = s.z * li; xs[clA + 3][mA] = s.w * li;
    }
    wsh[clA][nB0] = pW0.x; wsh[clA + 1][nB0] = pW0.y;
    wsh[clA + 2][nB0] = pW0.z; wsh[clA + 3][nB0] = pW0.w;
    wsh[clA][nB1] = pW1.x; wsh[clA + 1][nB1] = pW1.y;
    wsh[clA + 2][nB1] = pW1.z; wsh[clA + 3][nB1] = pW1.w;
    __syncthreads();
    if (kc < 15) {  // prefetch next kc during compute
      int h2 = (kc + 1) >> 1, d2 = ((kc + 1) & 1) * 32;
      if (tid < 128) {
#pragma unroll
        for (int sp = 0; sp < SPLIT; ++sp)
          pA[sp] = *(const float4*)(
              Op + (long)((sp * 16 + b * 8 + h2) * 192 + t0 + mA) * 64 + d2 +
              clA);
      }
      pW0 = *(const float4*)(cw + (long)(n0 + nB0) * 512 + h2 * 64 + d2 + clA);
      pW1 = *(const float4*)(cw + (long)(n0 + nB1) * 512 + h2 * 64 + d2 + clA);
    }
#pragma unroll
    for (int c = 0; c < 32; ++c) {
      float a = xs[c][m];
      float4 bv = *(const float4*)&wsh[c][nq * 4];
      acc[0] += a * bv.x; acc[1] += a * bv.y;
      acc[2] += a * bv.z; acc[3] += a * bv.w;
    }
    __syncthreads();
  }

  float4 bias = *(const float4*)(cb + n0 + nq * 4);
  float4 st;
  st.x = acc[0] + bias.x;
  st.y = acc[1] + bias.y;
  st.z = acc[2] + bias.z;
  st.w = acc[3] + bias.w;
  *(float4*)(out + (long)(b * 192 + t0 + m) * 512 + n0 + nq * 4) = st;
}

extern "C" void kernel_launch(void* const* d_in, const int* in_sizes, int n_in,
                              void* d_out, int out_size, void* d_ws, size_t ws_size,
                              hipStream_t stream) {
  const float* x0 = (const float*)d_in[0];
  const float* x1 = (const float*)d_in[1];
  const float* x2 = (const float*)d_in[2];
  const float* qw = (const float*)d_in[3];
  const float* qb = (const float*)d_in[4];
  const float* kw = (const float*)d_in[5];
  const float* kb = (const float*)d_in[6];
  const float* vw = (const float*)d_in[7];
  const float* vb = (const float*)d_in[8];
  const float* cw = (const float*)d_in[9];
  const float* cb = (const float*)d_in[10];
  float* out = (float*)d_out;

  // workspace carve
  char* ws = (char*)d_ws;
  float* Q0f = (float*)(ws + 0);        // 16*192*64 f32 (pre-scaled by ESC)
  float* K1f = (float*)(ws + 786432);   // 16*192*64 f32
  float* V1f = (float*)(ws + 1572864);  // 16*192*64 f32
  u16* K2b = (u16*)(ws + 2359296);      // 16*192*64 bf16
  u16* V2b = (u16*)(ws + 2752512);      // 16*192*64 bf16
  float* Op = (float*)(ws + 3145728);   // SPLIT*16*192*64 f32
  float* lp = (float*)(ws + 3145728 + (size_t)SPLIT * 786432);

  proj_kernel<<<80, 256, 0, stream>>>(x0, x1, x2, qw, qb, kw, kb, vw, vb,
                                      Q0f, K1f, V1f, K2b, V2b);
  attn_kernel<<<SPLIT * 192, 256, 52224, stream>>>(Q0f, K1f, V1f, K2b, V2b,
                                                   Op, lp);
  outproj_kernel<<<192, 256, 0, stream>>>(Op, lp, cw, cb, out);
}